// Round 1
// baseline (365.839 us; speedup 1.0000x reference)
//
#include <hip/hip_runtime.h>
#include <math.h>

#define CAP   32768
#define NB    32
#define CD    64
#define ROWS  64
#define NBLK  (CAP / ROWS)   // 512
#define TOPK  16
#define CEPS  1e-8f

// workspace layout (floats)
#define WS_QP    0            // [32][64] q_part + b1
#define WS_QN    2048         // [32][64] normalized query context
#define WS_FINAL 4096         // [32][32768] final scores

#define PITCH 68              // LDS row pitch (floats): 64 + 4 pad, 16B-aligned rows

__global__ __launch_bounds__(64) void prep_kernel(
    const float* __restrict__ qc,    // [32][64] query_content
    const float* __restrict__ qctx,  // [32][64] query_context
    const float* __restrict__ W1,    // [128][64]
    const float* __restrict__ b1,    // [64]
    float* __restrict__ ws)
{
    const int b = blockIdx.x;
    const int j = threadIdx.x;

    // q_part[b][j] = sum_i qc[b][i] * W1[i][j] + b1[j]
    float acc = b1[j];
    #pragma unroll 8
    for (int i = 0; i < 64; ++i)
        acc = fmaf(qc[b * 64 + i], W1[i * 64 + j], acc);
    ws[WS_QP + b * 64 + j] = acc;

    // normalized query context
    float x = qctx[b * 64 + j];
    float ss = x * x;
    ss += __shfl_xor(ss, 1,  64);
    ss += __shfl_xor(ss, 2,  64);
    ss += __shfl_xor(ss, 4,  64);
    ss += __shfl_xor(ss, 8,  64);
    ss += __shfl_xor(ss, 16, 64);
    ss += __shfl_xor(ss, 32, 64);
    float nrm = fmaxf(sqrtf(ss), CEPS);
    ws[WS_QN + b * 64 + j] = x / nrm;
}

__device__ __forceinline__ void acc_pair(const float4 qp, const float4 qn,
                                         const float4 m, const float4 xv,
                                         const float4 w2, float& a1, float& a2)
{
    a1 = fmaf(fmaxf(qp.x + m.x, 0.f), w2.x, a1);
    a1 = fmaf(fmaxf(qp.y + m.y, 0.f), w2.y, a1);
    a1 = fmaf(fmaxf(qp.z + m.z, 0.f), w2.z, a1);
    a1 = fmaf(fmaxf(qp.w + m.w, 0.f), w2.w, a1);
    a2 = fmaf(qn.x, xv.x, a2);
    a2 = fmaf(qn.y, xv.y, a2);
    a2 = fmaf(qn.z, xv.z, a2);
    a2 = fmaf(qn.w, xv.w, a2);
}

__global__ __launch_bounds__(256) void score_kernel(
    const float* __restrict__ mcont,  // [CAP][64]
    const float* __restrict__ mctx,   // [CAP][64]
    const float* __restrict__ fresh,  // [CAP]
    const float* __restrict__ W1,     // [128][64]
    const float* __restrict__ W2,     // [64]
    const float* __restrict__ b2,     // [1]
    float* __restrict__ ws)
{
    __shared__ float s_mc[ROWS * PITCH];
    __shared__ float s_mx[ROWS * PITCH];
    __shared__ float s_mp[ROWS * PITCH];
    __shared__ float s_qp[NB * PITCH];
    __shared__ float s_qn[NB * PITCH];
    __shared__ float s_w2[64];
    __shared__ float s_base[ROWS];   // 0.2 * freshness
    __shared__ float s_inv[ROWS];    // 0.3 / max(||mctx||, eps)

    const int tid = threadIdx.x;
    const int lane = tid & 63;
    const int C0 = blockIdx.x * ROWS;

    // ---- cooperative global -> LDS (float4, coalesced) ----
    const float4* g_mc = (const float4*)(mcont + (size_t)C0 * 64);
    const float4* g_mx = (const float4*)(mctx  + (size_t)C0 * 64);
    #pragma unroll
    for (int t = tid; t < ROWS * 16; t += 256) {
        int r = t >> 4, c4 = t & 15;
        *(float4*)&s_mc[r * PITCH + c4 * 4] = g_mc[t];
        *(float4*)&s_mx[r * PITCH + c4 * 4] = g_mx[t];
    }
    const float4* g_qp = (const float4*)(ws + WS_QP);
    const float4* g_qn = (const float4*)(ws + WS_QN);
    #pragma unroll
    for (int t = tid; t < NB * 16; t += 256) {
        int r = t >> 4, c4 = t & 15;
        *(float4*)&s_qp[r * PITCH + c4 * 4] = g_qp[t];
        *(float4*)&s_qn[r * PITCH + c4 * 4] = g_qn[t];
    }
    if (tid < 64) {
        s_w2[tid]   = W2[tid];
        s_base[tid] = 0.2f * fresh[C0 + tid];
    }

    // W1 lower-half column `lane` into registers (coalesced across lanes, L1-cached)
    float w1c[64];
    #pragma unroll
    for (int i = 0; i < 64; ++i)
        w1c[i] = W1[(64 + i) * 64 + lane];

    __syncthreads();

    // ---- phase A: m_part rows + context inv-norms (one wave -> 16 rows) ----
    const int wv = tid >> 6;
    for (int r = 0; r < 16; ++r) {
        const int c = wv * 16 + r;
        const float* row = &s_mc[c * PITCH];
        float acc = 0.f;
        #pragma unroll
        for (int i4 = 0; i4 < 16; ++i4) {
            float4 m = *(const float4*)&row[i4 * 4];   // broadcast read
            acc = fmaf(m.x, w1c[4 * i4 + 0], acc);
            acc = fmaf(m.y, w1c[4 * i4 + 1], acc);
            acc = fmaf(m.z, w1c[4 * i4 + 2], acc);
            acc = fmaf(m.w, w1c[4 * i4 + 3], acc);
        }
        s_mp[c * PITCH + lane] = acc;

        float x = s_mx[c * PITCH + lane];
        float ss = x * x;
        ss += __shfl_xor(ss, 1,  64);
        ss += __shfl_xor(ss, 2,  64);
        ss += __shfl_xor(ss, 4,  64);
        ss += __shfl_xor(ss, 8,  64);
        ss += __shfl_xor(ss, 16, 64);
        ss += __shfl_xor(ss, 32, 64);
        if (lane == 0)
            s_inv[c] = 0.3f / fmaxf(sqrtf(ss), CEPS);
    }
    __syncthreads();

    // ---- phase B: 2 b x 4 c pairs per thread ----
    const int bq = (tid & 15) << 1;   // b0, handles bq, bq+1
    const int cq = (tid >> 4) << 2;   // c0, handles cq..cq+3
    float a1[2][4] = {{0.f}}, a2[2][4] = {{0.f}};

    #pragma unroll 4
    for (int j4 = 0; j4 < 16; ++j4) {
        const int jo = j4 * 4;
        float4 w2v  = *(const float4*)&s_w2[jo];
        float4 qp0  = *(const float4*)&s_qp[ bq      * PITCH + jo];
        float4 qp1  = *(const float4*)&s_qp[(bq + 1) * PITCH + jo];
        float4 qn0  = *(const float4*)&s_qn[ bq      * PITCH + jo];
        float4 qn1  = *(const float4*)&s_qn[(bq + 1) * PITCH + jo];
        #pragma unroll
        for (int ci = 0; ci < 4; ++ci) {
            float4 mv = *(const float4*)&s_mp[(cq + ci) * PITCH + jo];
            float4 xv = *(const float4*)&s_mx[(cq + ci) * PITCH + jo];
            acc_pair(qp0, qn0, mv, xv, w2v, a1[0][ci], a2[0][ci]);
            acc_pair(qp1, qn1, mv, xv, w2v, a1[1][ci], a2[1][ci]);
        }
    }

    const float b2v = b2[0];
    #pragma unroll
    for (int bi = 0; bi < 2; ++bi) {
        #pragma unroll
        for (int ci = 0; ci < 4; ++ci) {
            const int b = bq + bi, c = cq + ci;
            float logit = a1[bi][ci] + b2v;
            float sig = 0.5f / (1.f + expf(-logit));
            float fin = sig + a2[bi][ci] * s_inv[c] + s_base[c];
            ws[WS_FINAL + (size_t)b * CAP + C0 + c] = fin;
        }
    }
}

__global__ __launch_bounds__(256) void topk_kernel(
    const float* __restrict__ mcont,  // [CAP][64]
    const float* __restrict__ fresh,  // [CAP]
    float* __restrict__ ws,
    float* __restrict__ out)
{
    __shared__ float sval[256];
    __shared__ int   sidx[256];
    __shared__ int   s_sel;

    const int b = blockIdx.x;
    const int tid = threadIdx.x;
    float* row = ws + WS_FINAL + (size_t)b * CAP;

    float* out_content = out;                       // [32][16][64]
    float* out_sim     = out + NB * TOPK * 64;      // [32][16]
    float* out_tw      = out + NB * TOPK * 64 + NB * TOPK;

    for (int k = 0; k < TOPK; ++k) {
        float best = -INFINITY;
        int   bidx = CAP;
        for (int i = tid; i < CAP; i += 256) {
            float v = row[i];
            if (v > best) { best = v; bidx = i; }  // strided i ascending: first hit = lowest idx
        }
        sval[tid] = best;
        sidx[tid] = bidx;
        __syncthreads();
        for (int s = 128; s > 0; s >>= 1) {
            if (tid < s) {
                float ov = sval[tid + s];
                int   oi = sidx[tid + s];
                if (ov > sval[tid] || (ov == sval[tid] && oi < sidx[tid])) {
                    sval[tid] = ov;
                    sidx[tid] = oi;
                }
            }
            __syncthreads();
        }
        if (tid == 0) {
            int idx = sidx[0];
            s_sel = idx;
            out_sim[b * TOPK + k] = sval[0];
            out_tw [b * TOPK + k] = fresh[idx];
            row[idx] = -INFINITY;   // remove from next pass
        }
        __syncthreads();
        int idx = s_sel;
        if (tid < 64)
            out_content[((size_t)b * TOPK + k) * 64 + tid] = mcont[(size_t)idx * 64 + tid];
        __syncthreads();
    }
}

extern "C" void kernel_launch(void* const* d_in, const int* in_sizes, int n_in,
                              void* d_out, int out_size, void* d_ws, size_t ws_size,
                              hipStream_t stream) {
    const float* qc    = (const float*)d_in[0];
    const float* qctx  = (const float*)d_in[1];
    const float* mcont = (const float*)d_in[2];
    const float* mctx  = (const float*)d_in[3];
    const float* fresh = (const float*)d_in[4];
    const float* W1    = (const float*)d_in[5];
    const float* b1    = (const float*)d_in[6];
    const float* W2    = (const float*)d_in[7];
    const float* b2    = (const float*)d_in[8];
    float* out = (float*)d_out;
    float* ws  = (float*)d_ws;

    prep_kernel<<<NB, 64, 0, stream>>>(qc, qctx, W1, b1, ws);
    score_kernel<<<NBLK, 256, 0, stream>>>(mcont, mctx, fresh, W1, W2, b2, ws);
    topk_kernel<<<NB, 256, 0, stream>>>(mcont, fresh, ws, out);
}

// Round 2
// 146.238 us; speedup vs baseline: 2.5017x; 2.5017x over previous
//
#include <hip/hip_runtime.h>
#include <math.h>

#define CAP   32768
#define NB    32
#define CD    64
#define ROWS  64
#define NBLK  (CAP / ROWS)   // 512
#define TOPK  16
#define CEPS  1e-8f

// workspace layout (floats)
#define WS_QP    0            // [32][64] q_part + b1
#define WS_QN    2048         // [32][64] normalized query context
#define WS_FINAL 4096         // [32][32768] final scores

#define PITCH 68              // LDS row pitch (floats): 64 + 4 pad, 16B-aligned rows

#define CHUNK 2048            // top-k phase-1 chunk (elements per block)
#define NCHUNK (CAP / CHUNK)  // 16

__global__ __launch_bounds__(64) void prep_kernel(
    const float* __restrict__ qc,    // [32][64] query_content
    const float* __restrict__ qctx,  // [32][64] query_context
    const float* __restrict__ W1,    // [128][64]
    const float* __restrict__ b1,    // [64]
    float* __restrict__ ws)
{
    const int b = blockIdx.x;
    const int j = threadIdx.x;

    // q_part[b][j] = sum_i qc[b][i] * W1[i][j] + b1[j]
    float acc = b1[j];
    #pragma unroll 8
    for (int i = 0; i < 64; ++i)
        acc = fmaf(qc[b * 64 + i], W1[i * 64 + j], acc);
    ws[WS_QP + b * 64 + j] = acc;

    // normalized query context
    float x = qctx[b * 64 + j];
    float ss = x * x;
    ss += __shfl_xor(ss, 1,  64);
    ss += __shfl_xor(ss, 2,  64);
    ss += __shfl_xor(ss, 4,  64);
    ss += __shfl_xor(ss, 8,  64);
    ss += __shfl_xor(ss, 16, 64);
    ss += __shfl_xor(ss, 32, 64);
    float nrm = fmaxf(sqrtf(ss), CEPS);
    ws[WS_QN + b * 64 + j] = x / nrm;
}

__device__ __forceinline__ void acc_pair(const float4 qp, const float4 qn,
                                         const float4 m, const float4 xv,
                                         const float4 w2, float& a1, float& a2)
{
    a1 = fmaf(fmaxf(qp.x + m.x, 0.f), w2.x, a1);
    a1 = fmaf(fmaxf(qp.y + m.y, 0.f), w2.y, a1);
    a1 = fmaf(fmaxf(qp.z + m.z, 0.f), w2.z, a1);
    a1 = fmaf(fmaxf(qp.w + m.w, 0.f), w2.w, a1);
    a2 = fmaf(qn.x, xv.x, a2);
    a2 = fmaf(qn.y, xv.y, a2);
    a2 = fmaf(qn.z, xv.z, a2);
    a2 = fmaf(qn.w, xv.w, a2);
}

__global__ __launch_bounds__(256) void score_kernel(
    const float* __restrict__ mcont,  // [CAP][64]
    const float* __restrict__ mctx,   // [CAP][64]
    const float* __restrict__ fresh,  // [CAP]
    const float* __restrict__ W1,     // [128][64]
    const float* __restrict__ W2,     // [64]
    const float* __restrict__ b2,     // [1]
    float* __restrict__ ws)
{
    __shared__ float s_mc[ROWS * PITCH];
    __shared__ float s_mx[ROWS * PITCH];
    __shared__ float s_mp[ROWS * PITCH];
    __shared__ float s_qp[NB * PITCH];
    __shared__ float s_qn[NB * PITCH];
    __shared__ float s_w2[64];
    __shared__ float s_base[ROWS];   // 0.2 * freshness
    __shared__ float s_inv[ROWS];    // 0.3 / max(||mctx||, eps)

    const int tid = threadIdx.x;
    const int lane = tid & 63;
    const int C0 = blockIdx.x * ROWS;

    // ---- cooperative global -> LDS (float4, coalesced) ----
    const float4* g_mc = (const float4*)(mcont + (size_t)C0 * 64);
    const float4* g_mx = (const float4*)(mctx  + (size_t)C0 * 64);
    #pragma unroll
    for (int t = tid; t < ROWS * 16; t += 256) {
        int r = t >> 4, c4 = t & 15;
        *(float4*)&s_mc[r * PITCH + c4 * 4] = g_mc[t];
        *(float4*)&s_mx[r * PITCH + c4 * 4] = g_mx[t];
    }
    const float4* g_qp = (const float4*)(ws + WS_QP);
    const float4* g_qn = (const float4*)(ws + WS_QN);
    #pragma unroll
    for (int t = tid; t < NB * 16; t += 256) {
        int r = t >> 4, c4 = t & 15;
        *(float4*)&s_qp[r * PITCH + c4 * 4] = g_qp[t];
        *(float4*)&s_qn[r * PITCH + c4 * 4] = g_qn[t];
    }
    if (tid < 64) {
        s_w2[tid]   = W2[tid];
        s_base[tid] = 0.2f * fresh[C0 + tid];
    }

    // W1 lower-half column `lane` into registers (coalesced across lanes, L1-cached)
    float w1c[64];
    #pragma unroll
    for (int i = 0; i < 64; ++i)
        w1c[i] = W1[(64 + i) * 64 + lane];

    __syncthreads();

    // ---- phase A: m_part rows + context inv-norms (one wave -> 16 rows) ----
    const int wv = tid >> 6;
    for (int r = 0; r < 16; ++r) {
        const int c = wv * 16 + r;
        const float* row = &s_mc[c * PITCH];
        float acc = 0.f;
        #pragma unroll
        for (int i4 = 0; i4 < 16; ++i4) {
            float4 m = *(const float4*)&row[i4 * 4];   // broadcast read
            acc = fmaf(m.x, w1c[4 * i4 + 0], acc);
            acc = fmaf(m.y, w1c[4 * i4 + 1], acc);
            acc = fmaf(m.z, w1c[4 * i4 + 2], acc);
            acc = fmaf(m.w, w1c[4 * i4 + 3], acc);
        }
        s_mp[c * PITCH + lane] = acc;

        float x = s_mx[c * PITCH + lane];
        float ss = x * x;
        ss += __shfl_xor(ss, 1,  64);
        ss += __shfl_xor(ss, 2,  64);
        ss += __shfl_xor(ss, 4,  64);
        ss += __shfl_xor(ss, 8,  64);
        ss += __shfl_xor(ss, 16, 64);
        ss += __shfl_xor(ss, 32, 64);
        if (lane == 0)
            s_inv[c] = 0.3f / fmaxf(sqrtf(ss), CEPS);
    }
    __syncthreads();

    // ---- phase B: 2 b x 4 c pairs per thread ----
    const int bq = (tid & 15) << 1;   // b0, handles bq, bq+1
    const int cq = (tid >> 4) << 2;   // c0, handles cq..cq+3
    float a1[2][4] = {{0.f}}, a2[2][4] = {{0.f}};

    #pragma unroll 4
    for (int j4 = 0; j4 < 16; ++j4) {
        const int jo = j4 * 4;
        float4 w2v  = *(const float4*)&s_w2[jo];
        float4 qp0  = *(const float4*)&s_qp[ bq      * PITCH + jo];
        float4 qp1  = *(const float4*)&s_qp[(bq + 1) * PITCH + jo];
        float4 qn0  = *(const float4*)&s_qn[ bq      * PITCH + jo];
        float4 qn1  = *(const float4*)&s_qn[(bq + 1) * PITCH + jo];
        #pragma unroll
        for (int ci = 0; ci < 4; ++ci) {
            float4 mv = *(const float4*)&s_mp[(cq + ci) * PITCH + jo];
            float4 xv = *(const float4*)&s_mx[(cq + ci) * PITCH + jo];
            acc_pair(qp0, qn0, mv, xv, w2v, a1[0][ci], a2[0][ci]);
            acc_pair(qp1, qn1, mv, xv, w2v, a1[1][ci], a2[1][ci]);
        }
    }

    const float b2v = b2[0];
    #pragma unroll
    for (int bi = 0; bi < 2; ++bi) {
        #pragma unroll
        for (int ci = 0; ci < 4; ++ci) {
            const int b = bq + bi, c = cq + ci;
            float logit = a1[bi][ci] + b2v;
            float sig = 0.5f / (1.f + expf(-logit));
            float fin = sig + a2[bi][ci] * s_inv[c] + s_base[c];
            ws[WS_FINAL + (size_t)b * CAP + C0 + c] = fin;
        }
    }
}

// ---- top-k phase 1: per (row, 2048-chunk) local top-16, register-resident ----
// Winners written back into the chunk's own score region (already consumed):
//   row[cbase + 0..15]  = winner values (descending)
//   row[cbase + 16..31] = winner global indices (bit-cast)
__global__ __launch_bounds__(256) void topk_part1(float* __restrict__ ws)
{
    __shared__ float cval[2][8];
    __shared__ int   cidx[2][8];

    const int tid = threadIdx.x;
    const int wv  = tid >> 6;
    const int lane = tid & 63;
    const int b = blockIdx.y;
    float* row = ws + WS_FINAL + (size_t)b * CAP;
    const int cbase = blockIdx.x * CHUNK;
    const int tbase = cbase + tid * 8;

    float4 v0 = *(const float4*)&row[tbase];
    float4 v1 = *(const float4*)&row[tbase + 4];
    float v[8] = {v0.x, v0.y, v0.z, v0.w, v1.x, v1.y, v1.z, v1.w};

    for (int k = 0; k < TOPK; ++k) {
        // local max over 8 registers (first hit on tie = lowest index)
        float bv = v[0]; int bj = 0;
        #pragma unroll
        for (int j = 1; j < 8; ++j)
            if (v[j] > bv) { bv = v[j]; bj = j; }
        int bi = tbase + bj;

        // wave butterfly (val, idx), tie-break lower idx
        #pragma unroll
        for (int off = 1; off < 64; off <<= 1) {
            float ov = __shfl_xor(bv, off, 64);
            int   oi = __shfl_xor(bi, off, 64);
            if (ov > bv || (ov == bv && oi < bi)) { bv = ov; bi = oi; }
        }
        if (lane == 0) { cval[k & 1][wv] = bv; cidx[k & 1][wv] = bi; }
        __syncthreads();

        float Wv = cval[k & 1][0]; int Wi = cidx[k & 1][0];
        #pragma unroll
        for (int w = 1; w < 4; ++w) {
            float ov = cval[k & 1][w]; int oi = cidx[k & 1][w];
            if (ov > Wv || (ov == Wv && oi < Wi)) { Wv = ov; Wi = oi; }
        }
        if (tid == 0) {
            row[cbase + k]        = Wv;
            row[cbase + TOPK + k] = __int_as_float(Wi);
        }
        // remove winner from its owner's registers (unrolled: no dynamic indexing)
        #pragma unroll
        for (int j = 0; j < 8; ++j)
            if (Wi == tbase + j) v[j] = -INFINITY;
    }
}

// ---- top-k phase 2: merge 16 chunks x 16 candidates -> global top-16 + gather ----
__global__ __launch_bounds__(256) void topk_part2(
    const float* __restrict__ mcont,  // [CAP][64]
    const float* __restrict__ fresh,  // [CAP]
    const float* __restrict__ ws,
    float* __restrict__ out)
{
    __shared__ float cval[2][8];
    __shared__ int   cidx[2][8];
    __shared__ int   swin[TOPK];

    const int tid = threadIdx.x;
    const int wv  = tid >> 6;
    const int lane = tid & 63;
    const int b = blockIdx.x;
    const float* row = ws + WS_FINAL + (size_t)b * CAP;

    float* out_content = out;                       // [32][16][64]
    float* out_sim     = out + NB * TOPK * 64;      // [32][16]
    float* out_tw      = out + NB * TOPK * 64 + NB * TOPK;

    const int chunk = tid >> 4, slot = tid & 15;
    float val = row[chunk * CHUNK + slot];
    int   idx = __float_as_int(row[chunk * CHUNK + TOPK + slot]);

    for (int k = 0; k < TOPK; ++k) {
        float bv = val; int bi = idx;
        #pragma unroll
        for (int off = 1; off < 64; off <<= 1) {
            float ov = __shfl_xor(bv, off, 64);
            int   oi = __shfl_xor(bi, off, 64);
            if (ov > bv || (ov == bv && oi < bi)) { bv = ov; bi = oi; }
        }
        if (lane == 0) { cval[k & 1][wv] = bv; cidx[k & 1][wv] = bi; }
        __syncthreads();

        float Wv = cval[k & 1][0]; int Wi = cidx[k & 1][0];
        #pragma unroll
        for (int w = 1; w < 4; ++w) {
            float ov = cval[k & 1][w]; int oi = cidx[k & 1][w];
            if (ov > Wv || (ov == Wv && oi < Wi)) { Wv = ov; Wi = oi; }
        }
        if (tid == 0) {
            out_sim[b * TOPK + k] = Wv;
            out_tw [b * TOPK + k] = fresh[Wi];
            swin[k] = Wi;
        }
        if (idx == Wi) val = -INFINITY;   // candidates have unique indices
    }
    __syncthreads();

    // gather retrieved_content: 16 rows x 64 floats
    for (int t = tid; t < TOPK * 64; t += 256)
        out_content[(size_t)b * TOPK * 64 + t] =
            mcont[(size_t)swin[t >> 6] * 64 + (t & 63)];
}

extern "C" void kernel_launch(void* const* d_in, const int* in_sizes, int n_in,
                              void* d_out, int out_size, void* d_ws, size_t ws_size,
                              hipStream_t stream) {
    const float* qc    = (const float*)d_in[0];
    const float* qctx  = (const float*)d_in[1];
    const float* mcont = (const float*)d_in[2];
    const float* mctx  = (const float*)d_in[3];
    const float* fresh = (const float*)d_in[4];
    const float* W1    = (const float*)d_in[5];
    const float* b1    = (const float*)d_in[6];
    const float* W2    = (const float*)d_in[7];
    const float* b2    = (const float*)d_in[8];
    float* out = (float*)d_out;
    float* ws  = (float*)d_ws;

    prep_kernel<<<NB, 64, 0, stream>>>(qc, qctx, W1, b1, ws);
    score_kernel<<<NBLK, 256, 0, stream>>>(mcont, mctx, fresh, W1, W2, b2, ws);
    topk_part1<<<dim3(NCHUNK, NB), 256, 0, stream>>>(ws);
    topk_part2<<<NB, 256, 0, stream>>>(mcont, fresh, ws, out);
}

// Round 3
// 144.428 us; speedup vs baseline: 2.5330x; 1.0125x over previous
//
#include <hip/hip_runtime.h>
#include <math.h>

#define CAP   32768
#define NB    32
#define CD    64
#define ROWS  64
#define NBLK  (CAP / ROWS)   // 512
#define TOPK  16
#define CEPS  1e-8f

// workspace layout (floats)
#define WS_QP    0            // [32][64] q_part + b1
#define WS_QN    2048         // [32][64] normalized query context
#define WS_FINAL 4096         // [32][32768] final scores

#define PITCH 68              // LDS row pitch (floats): 64 + 4 pad, 16B-aligned rows

#define CHUNK 2048            // top-k phase-1 chunk (elements per block)
#define NCHUNK (CAP / CHUNK)  // 16

__global__ __launch_bounds__(64) void prep_kernel(
    const float* __restrict__ qc,    // [32][64] query_content
    const float* __restrict__ qctx,  // [32][64] query_context
    const float* __restrict__ W1,    // [128][64]
    const float* __restrict__ b1,    // [64]
    float* __restrict__ ws)
{
    const int b = blockIdx.x;
    const int j = threadIdx.x;

    // q_part[b][j] = sum_i qc[b][i] * W1[i][j] + b1[j], 4 independent chains
    float a0 = b1[j], a1 = 0.f, a2 = 0.f, a3 = 0.f;
    #pragma unroll
    for (int i = 0; i < 64; i += 4) {
        a0 = fmaf(qc[b * 64 + i + 0], W1[(i + 0) * 64 + j], a0);
        a1 = fmaf(qc[b * 64 + i + 1], W1[(i + 1) * 64 + j], a1);
        a2 = fmaf(qc[b * 64 + i + 2], W1[(i + 2) * 64 + j], a2);
        a3 = fmaf(qc[b * 64 + i + 3], W1[(i + 3) * 64 + j], a3);
    }
    ws[WS_QP + b * 64 + j] = (a0 + a1) + (a2 + a3);

    // normalized query context
    float x = qctx[b * 64 + j];
    float ss = x * x;
    ss += __shfl_xor(ss, 1,  64);
    ss += __shfl_xor(ss, 2,  64);
    ss += __shfl_xor(ss, 4,  64);
    ss += __shfl_xor(ss, 8,  64);
    ss += __shfl_xor(ss, 16, 64);
    ss += __shfl_xor(ss, 32, 64);
    float nrm = fmaxf(sqrtf(ss), CEPS);
    ws[WS_QN + b * 64 + j] = x / nrm;
}

__device__ __forceinline__ void acc_pair(const float4 qp, const float4 qn,
                                         const float4 m, const float4 xv,
                                         const float4 w2, float& a1, float& a2)
{
    a1 = fmaf(fmaxf(qp.x + m.x, 0.f), w2.x, a1);
    a1 = fmaf(fmaxf(qp.y + m.y, 0.f), w2.y, a1);
    a1 = fmaf(fmaxf(qp.z + m.z, 0.f), w2.z, a1);
    a1 = fmaf(fmaxf(qp.w + m.w, 0.f), w2.w, a1);
    a2 = fmaf(qn.x, xv.x, a2);
    a2 = fmaf(qn.y, xv.y, a2);
    a2 = fmaf(qn.z, xv.z, a2);
    a2 = fmaf(qn.w, xv.w, a2);
}

__global__ __launch_bounds__(256) void score_kernel(
    const float* __restrict__ mcont,  // [CAP][64]
    const float* __restrict__ mctx,   // [CAP][64]
    const float* __restrict__ fresh,  // [CAP]
    const float* __restrict__ W1,     // [128][64]
    const float* __restrict__ W2,     // [64]
    const float* __restrict__ b2,     // [1]
    float* __restrict__ ws)
{
    __shared__ float s_mc[ROWS * PITCH];   // memory_content tile; reused as output stage
    __shared__ float s_mx[ROWS * PITCH];
    __shared__ float s_mp[ROWS * PITCH];
    __shared__ float s_qp[NB * PITCH];
    __shared__ float s_qn[NB * PITCH];
    __shared__ float s_w2[64];
    __shared__ float s_base[ROWS];   // 0.2 * freshness
    __shared__ float s_inv[ROWS];    // 0.3 / max(||mctx||, eps)

    const int tid = threadIdx.x;
    const int lane = tid & 63;
    const int C0 = blockIdx.x * ROWS;

    // ---- cooperative global -> LDS (float4, coalesced) ----
    const float4* g_mc = (const float4*)(mcont + (size_t)C0 * 64);
    const float4* g_mx = (const float4*)(mctx  + (size_t)C0 * 64);
    #pragma unroll
    for (int t = tid; t < ROWS * 16; t += 256) {
        int r = t >> 4, c4 = t & 15;
        *(float4*)&s_mc[r * PITCH + c4 * 4] = g_mc[t];
        *(float4*)&s_mx[r * PITCH + c4 * 4] = g_mx[t];
    }
    const float4* g_qp = (const float4*)(ws + WS_QP);
    const float4* g_qn = (const float4*)(ws + WS_QN);
    #pragma unroll
    for (int t = tid; t < NB * 16; t += 256) {
        int r = t >> 4, c4 = t & 15;
        *(float4*)&s_qp[r * PITCH + c4 * 4] = g_qp[t];
        *(float4*)&s_qn[r * PITCH + c4 * 4] = g_qn[t];
    }
    if (tid < 64) {
        s_w2[tid]   = W2[tid];
        s_base[tid] = 0.2f * fresh[C0 + tid];
    }

    // W1 lower-half column `lane` into registers (coalesced across lanes, L2-cached)
    float w1c[64];
    #pragma unroll
    for (int i = 0; i < 64; ++i)
        w1c[i] = W1[(64 + i) * 64 + lane];

    __syncthreads();

    // ---- phase A: m_part rows + context inv-norms (one wave -> 16 rows) ----
    const int wv = tid >> 6;
    for (int r = 0; r < 16; ++r) {
        const int c = wv * 16 + r;
        const float* row = &s_mc[c * PITCH];
        float a0 = 0.f, a1 = 0.f, a2 = 0.f, a3 = 0.f;   // 4 independent chains
        #pragma unroll
        for (int i4 = 0; i4 < 16; i4 += 4) {
            float4 m0 = *(const float4*)&row[(i4 + 0) * 4];
            float4 m1 = *(const float4*)&row[(i4 + 1) * 4];
            float4 m2 = *(const float4*)&row[(i4 + 2) * 4];
            float4 m3 = *(const float4*)&row[(i4 + 3) * 4];
            a0 = fmaf(m0.x, w1c[4*i4+ 0], a0); a0 = fmaf(m0.y, w1c[4*i4+ 1], a0);
            a0 = fmaf(m0.z, w1c[4*i4+ 2], a0); a0 = fmaf(m0.w, w1c[4*i4+ 3], a0);
            a1 = fmaf(m1.x, w1c[4*i4+ 4], a1); a1 = fmaf(m1.y, w1c[4*i4+ 5], a1);
            a1 = fmaf(m1.z, w1c[4*i4+ 6], a1); a1 = fmaf(m1.w, w1c[4*i4+ 7], a1);
            a2 = fmaf(m2.x, w1c[4*i4+ 8], a2); a2 = fmaf(m2.y, w1c[4*i4+ 9], a2);
            a2 = fmaf(m2.z, w1c[4*i4+10], a2); a2 = fmaf(m2.w, w1c[4*i4+11], a2);
            a3 = fmaf(m3.x, w1c[4*i4+12], a3); a3 = fmaf(m3.y, w1c[4*i4+13], a3);
            a3 = fmaf(m3.z, w1c[4*i4+14], a3); a3 = fmaf(m3.w, w1c[4*i4+15], a3);
        }
        s_mp[c * PITCH + lane] = (a0 + a1) + (a2 + a3);

        float x = s_mx[c * PITCH + lane];
        float ss = x * x;
        ss += __shfl_xor(ss, 1,  64);
        ss += __shfl_xor(ss, 2,  64);
        ss += __shfl_xor(ss, 4,  64);
        ss += __shfl_xor(ss, 8,  64);
        ss += __shfl_xor(ss, 16, 64);
        ss += __shfl_xor(ss, 32, 64);
        if (lane == 0)
            s_inv[c] = 0.3f / fmaxf(sqrtf(ss), CEPS);
    }
    __syncthreads();

    // ---- phase B: 2 b x 4 c pairs per thread ----
    const int bq = (tid & 15) << 1;   // b0, handles bq, bq+1
    const int cq = (tid >> 4) << 2;   // c0, handles cq..cq+3
    float a1[2][4] = {{0.f}}, a2[2][4] = {{0.f}};

    #pragma unroll 4
    for (int j4 = 0; j4 < 16; ++j4) {
        const int jo = j4 * 4;
        float4 w2v  = *(const float4*)&s_w2[jo];
        float4 qp0  = *(const float4*)&s_qp[ bq      * PITCH + jo];
        float4 qp1  = *(const float4*)&s_qp[(bq + 1) * PITCH + jo];
        float4 qn0  = *(const float4*)&s_qn[ bq      * PITCH + jo];
        float4 qn1  = *(const float4*)&s_qn[(bq + 1) * PITCH + jo];
        #pragma unroll
        for (int ci = 0; ci < 4; ++ci) {
            float4 mv = *(const float4*)&s_mp[(cq + ci) * PITCH + jo];
            float4 xv = *(const float4*)&s_mx[(cq + ci) * PITCH + jo];
            acc_pair(qp0, qn0, mv, xv, w2v, a1[0][ci], a2[0][ci]);
            acc_pair(qp1, qn1, mv, xv, w2v, a1[1][ci], a2[1][ci]);
        }
    }

    // stage results in LDS (s_mc is dead after phase A), then coalesced store
    const float b2v = b2[0];
    #pragma unroll
    for (int bi = 0; bi < 2; ++bi) {
        #pragma unroll
        for (int ci = 0; ci < 4; ++ci) {
            const int b = bq + bi, c = cq + ci;
            float logit = a1[bi][ci] + b2v;
            float sig = 0.5f / (1.f + expf(-logit));
            s_mc[b * PITCH + c] = sig + a2[bi][ci] * s_inv[c] + s_base[c];
        }
    }
    __syncthreads();

    #pragma unroll
    for (int it = 0; it < 2; ++it) {
        int idx = it * 256 + tid;        // 0..511: 512 float4 = 32 b x 64 c
        int b = idx >> 4, c4 = idx & 15;
        *(float4*)&ws[WS_FINAL + (size_t)b * CAP + C0 + c4 * 4] =
            *(const float4*)&s_mc[b * PITCH + c4 * 4];
    }
}

// ---- top-k phase 1: one wave per (row, 2048-chunk), register-resident, no barriers ----
// Winner write-back into the chunk's own (consumed) score region:
//   row[cbase + 0..15]  = winner values (descending)
//   row[cbase + 16..31] = winner global indices (bit-cast)
__global__ __launch_bounds__(64) void topk_part1(float* __restrict__ ws)
{
    const int lane = threadIdx.x;
    const int b = blockIdx.y;
    float* row = ws + WS_FINAL + (size_t)b * CAP;
    const int cbase = blockIdx.x * CHUNK;

    // interleaved layout: v[j] holds global index cbase + j*64 + lane (coalesced loads)
    float v[32];
    #pragma unroll
    for (int j = 0; j < 32; ++j)
        v[j] = row[cbase + j * 64 + lane];

    float outv = 0.f;
    int   outi = 0;

    for (int k = 0; k < TOPK; ++k) {
        // local argmax (ascending j scan -> lowest idx wins ties within lane)
        float bv = v[0]; int bj = 0;
        #pragma unroll
        for (int j = 1; j < 32; ++j)
            if (v[j] > bv) { bv = v[j]; bj = j; }
        int bi = cbase + bj * 64 + lane;

        // wave butterfly on (val, idx), tie-break lower idx
        #pragma unroll
        for (int off = 1; off < 64; off <<= 1) {
            float ov = __shfl_xor(bv, off, 64);
            int   oi = __shfl_xor(bi, off, 64);
            if (ov > bv || (ov == bv && oi < bi)) { bv = ov; bi = oi; }
        }
        if (lane == k) { outv = bv; outi = bi; }   // lane k stashes k-th winner

        // removal: only the owning lane's register changes
        int rel = bi - cbase;
        bool mine = ((rel & 63) == lane);
        int wj = rel >> 6;
        #pragma unroll
        for (int j = 0; j < 32; ++j)
            if (mine && wj == j) v[j] = -INFINITY;
    }

    if (lane < TOPK) {
        row[cbase + lane]        = outv;
        row[cbase + TOPK + lane] = __int_as_float(outi);
    }
}

// ---- top-k phase 2: one wave per row, merge 16x16 candidates + fused gather ----
__global__ __launch_bounds__(64) void topk_part2(
    const float* __restrict__ mcont,  // [CAP][64]
    const float* __restrict__ fresh,  // [CAP]
    const float* __restrict__ ws,
    float* __restrict__ out)
{
    const int lane = threadIdx.x;
    const int b = blockIdx.x;
    const float* row = ws + WS_FINAL + (size_t)b * CAP;

    float* out_content = out;                       // [32][16][64]
    float* out_sim     = out + NB * TOPK * 64;      // [32][16]
    float* out_tw      = out + NB * TOPK * 64 + NB * TOPK;

    // 4 candidates per lane: chunk = lane&15, slots (lane>>4) + 4s
    const int chunk = lane & 15;
    const int s0 = lane >> 4;
    float v[4]; int iv[4];
    #pragma unroll
    for (int s = 0; s < 4; ++s) {
        v[s]  = row[chunk * CHUNK + s0 + 4 * s];
        iv[s] = __float_as_int(row[chunk * CHUNK + TOPK + s0 + 4 * s]);
    }

    float wval = 0.f; int widx = 0;
    for (int k = 0; k < TOPK; ++k) {
        float bv = v[0]; int bi = iv[0];
        #pragma unroll
        for (int s = 1; s < 4; ++s)
            if (v[s] > bv || (v[s] == bv && iv[s] < bi)) { bv = v[s]; bi = iv[s]; }
        #pragma unroll
        for (int off = 1; off < 64; off <<= 1) {
            float ov = __shfl_xor(bv, off, 64);
            int   oi = __shfl_xor(bi, off, 64);
            if (ov > bv || (ov == bv && oi < bi)) { bv = ov; bi = oi; }
        }
        if (lane == k) { wval = bv; widx = bi; }
        #pragma unroll
        for (int s = 0; s < 4; ++s)
            if (iv[s] == bi) v[s] = -INFINITY;   // candidate indices are unique
    }

    if (lane < TOPK) {
        out_sim[b * TOPK + lane] = wval;
        out_tw [b * TOPK + lane] = fresh[widx];
    }

    // fused gather: broadcast winner indices, copy 16 rows x 64 floats
    #pragma unroll
    for (int r = 0; r < TOPK; ++r) {
        int wi = __shfl(widx, r, 64);
        out_content[(size_t)b * TOPK * 64 + r * 64 + lane] =
            mcont[(size_t)wi * 64 + lane];
    }
}

extern "C" void kernel_launch(void* const* d_in, const int* in_sizes, int n_in,
                              void* d_out, int out_size, void* d_ws, size_t ws_size,
                              hipStream_t stream) {
    const float* qc    = (const float*)d_in[0];
    const float* qctx  = (const float*)d_in[1];
    const float* mcont = (const float*)d_in[2];
    const float* mctx  = (const float*)d_in[3];
    const float* fresh = (const float*)d_in[4];
    const float* W1    = (const float*)d_in[5];
    const float* b1    = (const float*)d_in[6];
    const float* W2    = (const float*)d_in[7];
    const float* b2    = (const float*)d_in[8];
    float* out = (float*)d_out;
    float* ws  = (float*)d_ws;

    prep_kernel<<<NB, 64, 0, stream>>>(qc, qctx, W1, b1, ws);
    score_kernel<<<NBLK, 256, 0, stream>>>(mcont, mctx, fresh, W1, W2, b2, ws);
    topk_part1<<<dim3(NCHUNK, NB), 64, 0, stream>>>(ws);
    topk_part2<<<NB, 64, 0, stream>>>(mcont, fresh, ws, out);
}